// Round 1
// baseline (25.027 us; speedup 1.0000x reference)
//
#include <hip/hip_runtime.h>
#include <hip/hip_bf16.h>

// Embedding gather: out[t, :] = weight[tokens[t], :]
// tokens: [8*2048] int, weight: [32000, 1024] fp32, out: [16384, 1024] fp32.
// One 256-thread block per token; each lane moves one float4 (16 B) —
// 256 lanes * 16 B = 4096 B = one full row. Fully coalesced both sides.

#define DIM 1024
#define VEC4_PER_ROW (DIM / 4)   // 256

__global__ __launch_bounds__(256) void embed_gather_kernel(
    const int* __restrict__ tokens,
    const float4* __restrict__ weight,   // [VOCAB][VEC4_PER_ROW]
    float4* __restrict__ out,            // [NTOK][VEC4_PER_ROW]
    int ntok)
{
    int t = blockIdx.x;
    if (t >= ntok) return;
    int tok = tokens[t];                      // scalar (wave-uniform) load
    const float4* src = weight + (size_t)tok * VEC4_PER_ROW;
    float4* dst = out + (size_t)t * VEC4_PER_ROW;
    dst[threadIdx.x] = src[threadIdx.x];
}

extern "C" void kernel_launch(void* const* d_in, const int* in_sizes, int n_in,
                              void* d_out, int out_size, void* d_ws, size_t ws_size,
                              hipStream_t stream) {
    const int*   tokens = (const int*)d_in[0];
    const float* weight = (const float*)d_in[1];
    float*       out    = (float*)d_out;

    int ntok = in_sizes[0];   // 8 * 2048 = 16384

    dim3 grid(ntok);
    dim3 block(256);
    embed_gather_kernel<<<grid, block, 0, stream>>>(
        tokens, (const float4*)weight, (float4*)out, ntok);
}